// Round 8
// baseline (201.225 us; speedup 1.0000x reference)
//
#include <hip/hip_runtime.h>

#define S_LEN 2048
#define NH 16
#define LOG2E 1.4426950408889634f

typedef _Float16 half8_t __attribute__((ext_vector_type(8)));
typedef _Float16 half4_t __attribute__((ext_vector_type(4)));
typedef _Float16 half2_t __attribute__((ext_vector_type(2)));
typedef float f32x4 __attribute__((ext_vector_type(4)));

__device__ __forceinline__ f32x4 mfma_qk(half8_t a, half8_t b, f32x4 c) {
  return __builtin_amdgcn_mfma_f32_16x16x32_f16(a, b, c, 0, 0, 0);
}
__device__ __forceinline__ void glds16(const void* g, void* l) {
  __builtin_amdgcn_global_load_lds(
      (const __attribute__((address_space(1))) unsigned int*)g,
      (__attribute__((address_space(3))) unsigned int*)l, 16, 0, 0);
}
__device__ __forceinline__ float fexp2(float x) {
#if __has_builtin(__builtin_amdgcn_exp2f)
  return __builtin_amdgcn_exp2f(x);   // raw v_exp_f32, 1 instr
#else
  return exp2f(x);
#endif
}

// ---------------- fused prep: fp32->fp16 cvts + both weight transposes ----------
__global__ __launch_bounds__(256) void prep_kernel(const float* __restrict__ x,
                                                   const float* __restrict__ pos_embed,
                                                   const float* __restrict__ W_pos,
                                                   const float* __restrict__ W_tok,
                                                   _Float16* __restrict__ x_f,
                                                   _Float16* __restrict__ pos_f,
                                                   _Float16* __restrict__ wt_pos,
                                                   _Float16* __restrict__ wt_tok) {
  __shared__ float tile[64][65];
  const int bid = blockIdx.x, tid = threadIdx.x;
  if (bid < 6144) {
    // elementwise cvt: 1,572,864 float4 total (pos_embed first 524288, then x)
    int id = bid * 256 + tid;
    const float* src; _Float16* dst;
    if (id < 524288) { src = pos_embed; dst = pos_f; }
    else { id -= 524288; src = x; dst = x_f; }
    float4 f = ((const float4*)src)[id];
    half4_t o = {(_Float16)f.x, (_Float16)f.y, (_Float16)f.z, (_Float16)f.w};
    ((half4_t*)dst)[id] = o;
    return;
  }
  // weight transpose fp32 [K,N] -> fp16 [N,K], K=1024
  const float* W; _Float16* Wt; int N, nx, ky;
  if (bid < 6656) { W = W_pos; Wt = wt_pos; N = 2048; int t = bid - 6144; nx = t & 31; ky = t >> 5; }
  else            { W = W_tok; Wt = wt_tok; N = 3072; int t = bid - 6656; nx = t % 48; ky = t / 48; }
  int k0 = ky * 64, n0 = nx * 64;
  int tx = tid & 63, ty = tid >> 6;
  for (int j = 0; j < 16; ++j) {
    int k = ty * 16 + j;
    tile[k][tx] = W[(size_t)(k0 + k) * N + n0 + tx];
  }
  __syncthreads();
  for (int j = 0; j < 16; ++j) {
    int n = ty * 16 + j;
    Wt[(size_t)(n0 + n) * 1024 + k0 + tx] = (_Float16)tile[tx][n];
  }
}

// ---------------- merged fp16 GEMM (pos + tok), fragment-layout epilogues ------
// blocks [0,256):   pos gemm  2048x2048, A=pos_f, Bt=wt_pos, kg=KGP, qr=QRp
// blocks [256,1024): tok gemm 4096x3072, A=x_f,  Bt=wt_tok, kg=KG,  qr=QRt, vg=VG
// 2-phase double-buffered K-loop (R7-verified). V epilogue now writes the
// PAIR-INTERLEAVED layout: tile = [pair p=mi>>1][d=ni][quad][l16][mi&1][4 keys]
// so flash reads a half8 = keys {16p..16p+3 x quads} || {16p+16..} per lane
// (conflict-free b128, feeds the K=32 PV fusion directly).
__global__ __launch_bounds__(256) void gemm_all_kernel(const _Float16* __restrict__ pos_f,
                                                       const _Float16* __restrict__ wt_pos,
                                                       const _Float16* __restrict__ x_f,
                                                       const _Float16* __restrict__ wt_tok,
                                                       _Float16* __restrict__ KGP,
                                                       _Float16* __restrict__ QRp,
                                                       _Float16* __restrict__ KG,
                                                       _Float16* __restrict__ QRt,
                                                       _Float16* __restrict__ VG,
                                                       float qscale) {
  __shared__ _Float16 SMem[16384];       // 32 KB: 2x (Ald|Bld) double-buffer
  _Float16* buf0 = SMem;                 // [0,4096)=A  [4096,8192)=B
  _Float16* buf1 = SMem + 8192;

  const int bid = blockIdx.x, tid = threadIdx.x;
  const _Float16 *A, *Bt; _Float16 *kg, *qr, *vg;
  int m0, n0;
  if (bid < 256) {
    A = pos_f; Bt = wt_pos; kg = KGP; qr = QRp; vg = nullptr;
    m0 = (bid >> 4) * 128; n0 = (bid & 15) * 128;
  } else {
    int t = bid - 256;
    A = x_f; Bt = wt_tok; kg = KG; qr = QRt; vg = VG;
    m0 = (t / 24) * 128; n0 = (t % 24) * 128;
  }
  const int K = 1024;

  const int wave = tid >> 6, lane = tid & 63;
  const int quad = lane >> 4, l16 = lane & 15;
  const int wm = (wave >> 1) * 64, wn = (wave & 1) * 64;

  f32x4 acc[4][4] = {};
  const int flat0 = tid, flat1 = tid + 256;
  const int r0 = flat0 >> 2, c0 = flat0 & 3;
  const int r1 = flat1 >> 2, c1 = flat1 & 3;

  auto stage = [&](int ko, _Float16* buf) {
    glds16(A + (size_t)(m0 + r0) * K + ko + c0 * 8, &buf[flat0 * 8]);
    glds16(Bt + (size_t)(n0 + r0) * K + ko + c0 * 8, &buf[4096 + flat0 * 8]);
    glds16(A + (size_t)(m0 + r1) * K + ko + c1 * 8, &buf[flat1 * 8]);
    glds16(Bt + (size_t)(n0 + r1) * K + ko + c1 * 8, &buf[4096 + flat1 * 8]);
  };
  auto kstep = [&](const _Float16* buf) {
    half8_t af[4], bfv[4];
    #pragma unroll
    for (int t = 0; t < 4; ++t) {
      af[t]  = *(const half8_t*)&buf[(wm + t * 16 + l16) * 32 + quad * 8];
      bfv[t] = *(const half8_t*)&buf[4096 + (wn + t * 16 + l16) * 32 + quad * 8];
    }
    #pragma unroll
    for (int mi = 0; mi < 4; ++mi)
      #pragma unroll
      for (int ni = 0; ni < 4; ++ni)
        acc[mi][ni] = mfma_qk(af[mi], bfv[ni], acc[mi][ni]);
  };

  stage(0, buf0);
  __syncthreads();
  #pragma unroll 1
  for (int ko = 0; ko < K; ko += 64) {
    stage(ko + 32, buf1);                 // next tile issues before compute
    kstep(buf0);
    __syncthreads();                      // readers done + buf1 loads landed
    if (ko + 64 < K) stage(ko + 64, buf0);
    kstep(buf1);
    __syncthreads();
  }
  // last barrier above also protects SMem before epilogue scratch reuse

  const int n_base = n0 + wn, m_base = m0 + wm;   // both 64-aligned
  const int bb = m_base >> 11;
  const int tile16 = (m_base & 2047) >> 6;

  if (n_base >= 2048) {
    // V region (tok only), pair-interleaved:
    // idx = ((mi>>1)*4 + ni)*512 + quad*128 + l16*8 + (mi&1)*4
    int hh = (n_base >> 6) & 15;
    _Float16* dstb = vg + (size_t)((bb * 16 + hh) * 32 + tile16) * 4096;
    #pragma unroll
    for (int mi = 0; mi < 4; ++mi)
      #pragma unroll
      for (int ni = 0; ni < 4; ++ni) {
        union { ushort4 u; _Float16 h[4]; } pk;
        #pragma unroll
        for (int r = 0; r < 4; ++r) pk.h[r] = (_Float16)acc[mi][ni][r];
        *(ushort4*)(dstb + ((mi >> 1) * 4 + ni) * 512 + quad * 128 + l16 * 8 +
                    (mi & 1) * 4) = pk.u;
      }
  } else if (n_base >= 1024) {
    // Q region: row-major, scaled
    #pragma unroll
    for (int mi = 0; mi < 4; ++mi)
      #pragma unroll
      for (int ni = 0; ni < 4; ++ni)
        #pragma unroll
        for (int r = 0; r < 4; ++r) {
          int m = m_base + mi * 16 + quad * 4 + r;
          int col = n_base - 1024 + ni * 16 + l16;
          qr[(size_t)m * 1024 + col] = (_Float16)(acc[mi][ni][r] * qscale);
        }
  } else {
    // K region: in-lane dim-transpose, 2 rounds of 32 keys through 4 KB/wave scratch
    int hh = n_base >> 6;
    int bhk = vg ? (bb * 16 + hh) : hh;
    _Float16* dstb = kg + (size_t)(bhk * 32 + tile16) * 4096;
    _Float16* Tr = SMem + wave * 2048;       // per-wave private 4 KB
    #pragma unroll
    for (int p = 0; p < 2; ++p) {
      #pragma unroll
      for (int mi2 = 0; mi2 < 2; ++mi2) {
        int mi = p * 2 + mi2;
        #pragma unroll
        for (int ni = 0; ni < 4; ++ni)
          #pragma unroll
          for (int r = 0; r < 4; ++r) {
            int keyp = mi2 * 16 + quad * 4 + r;            // 0..31
            int dim = ni * 16 + l16;
            int col = (((dim >> 3) ^ (keyp & 7)) << 3) | (dim & 7);
            Tr[keyp * 64 + col] = (_Float16)acc[mi][ni][r];
          }
      }
      #pragma unroll
      for (int j = 0; j < 4; ++j) {
        int wkp = j >> 1, kfl = j & 1;
        int wk = p * 2 + wkp;
        half8_t v = *(const half8_t*)&Tr[(wkp * 16 + l16) * 64 +
                                         (((kfl * 4 + quad) ^ (l16 & 7)) << 3)];
        *(half8_t*)(dstb + wk * 1024 + kfl * 512 + quad * 128 + l16 * 8) = v;
      }
    }
  }
}

// ---------------- fused flash attention v10: 8-wave LDS-shared K/V ----------------
// 256 q-rows/block, grid 256 (1 block/CU). 8 waves = 2 key-halves (kw) x 4
// q-quarters (qw); each wave = 64 q-rows (R3's verified qt=4 math) x 32 keys
// per 64-key tile. K/V double-buffered in LDS via glds16 (same discipline as
// the gemm); per-tile: stage t+1, compute t, one barrier. PV uses the K=32
// fragment-pair fusion (pairs within tile, enabled by the new VG layout).
// Cross-half O combine: 2-round LDS reduction overlaid on dead K/V buffers.
// L2 panel traffic drops 4x vs the 64-row blocking; K frags no longer live
// in registers (R4-R6 spill wall removed at the source).
__global__ __launch_bounds__(512, 2) void flash_kernel(const _Float16* __restrict__ QRt,
                                                       const _Float16* __restrict__ QRp,
                                                       const _Float16* __restrict__ KG,
                                                       const _Float16* __restrict__ KGP,
                                                       const _Float16* __restrict__ VG,
                                                       const float* __restrict__ bias_table,
                                                       float* __restrict__ out) {
  __shared__ __align__(16) unsigned char SM[51712];
  _Float16* SK = (_Float16*)SM;             // [2][12288] halfs: Ktok|Kpos|V dbuf
  float* ored  = (float*)SM;                // [4][64][36] fp32, overlay after loop
  float* biasl = (float*)(SM + 49152);      // 384 floats
  float* lred  = (float*)(SM + 50688);      // [4][64] floats

  const int tid = threadIdx.x;
  const int wave = tid >> 6, lane = tid & 63;
  const int quad = lane >> 4, l16 = lane & 15;
  const int qw = wave & 3, kw = wave >> 2;
  const int lbid = blockIdx.x;
  const int q0 = ((lbid >> 3) & 7) * 256;        // 8 q-blocks per bh
  const int bh = (lbid & 7) + 8 * (lbid >> 6);   // bh's q-blocks share one XCD
  const int b = bh >> 4, h = bh & 15;

  if (tid < 384) {
    int i = tid;
    int delta = i - 192;
    int n = -delta;
    int ret = (n < 0) ? 16 : 0;
    int na = (n < 0) ? -n : n;
    int bkt;
    if (na < 8) bkt = na;
    else {
      int s2 = (na >= 12) + (na >= 16) + (na >= 23) + (na >= 32) +
               (na >= 46) + (na >= 64) + (na >= 91) + (na >= 128);
      bkt = 8 + s2; if (bkt > 15) bkt = 15;
    }
    bkt += ret;
    biasl[i] = bias_table[(size_t)(2048 + bkt) * NH + h] * LOG2E;
  }
  const float b_lo = bias_table[(2048 + 15) * NH + h] * LOG2E;
  const float b_hi = bias_table[(2048 + 31) * NH + h] * LOG2E;

  // Q fragments (pre-scaled in gemm epilogue); wave's rows = q0+qw*64+qt*16+l16
  const int qbase = q0 + qw * 64;
  half8_t qf[4][4];
  {
    const _Float16* tq = QRt + (size_t)(b * S_LEN + qbase + l16) * 1024 + h * 64 + quad * 8;
    const _Float16* pq = QRp + (size_t)(qbase + l16) * 1024 + h * 64 + quad * 8;
    #pragma unroll
    for (int qt = 0; qt < 4; ++qt)
      #pragma unroll
      for (int kf = 0; kf < 2; ++kf) {
        qf[kf][qt]     = *(const half8_t*)(tq + (size_t)qt * 16 * 1024 + kf * 32);
        qf[kf + 2][qt] = *(const half8_t*)(pq + (size_t)qt * 16 * 1024 + kf * 32);
      }
  }

  const _Float16* kgp = KG  + (size_t)bh * 131072;
  const _Float16* kpp = KGP + (size_t)h  * 131072;
  const _Float16* vgp = VG  + (size_t)bh * 131072;

  auto stage = [&](int t, int par) {
    _Float16* dst = SK + par * 12288;
    glds16(kgp + (size_t)t * 4096 + tid * 8, dst + tid * 8);
    glds16(kpp + (size_t)t * 4096 + tid * 8, dst + 4096 + tid * 8);
    glds16(vgp + (size_t)t * 4096 + tid * 8, dst + 8192 + tid * 8);
  };

  f32x4 oa[4][4] = {};
  float lpart[4] = {0.f, 0.f, 0.f, 0.f};
  union VP8 { half8_t h8; struct { half4_t lo, hi; } p; };

  stage(0, 0);
  __syncthreads();   // also covers biasl

  #pragma unroll 1
  for (int t = 0; t < 32; ++t) {
    if (t != 31) stage(t + 1, (t + 1) & 1);
    const _Float16* Bse = SK + (t & 1) * 12288;
    const int dk = t * 64 - q0 - qw * 64;   // 64-granular
    VP8 pc[4];
    #pragma unroll
    for (int j = 0; j < 2; ++j) {
      const int f = kw * 2 + j;             // keyfrag 0..3
      half8_t kf_[4];
      kf_[0] = *(const half8_t*)&Bse[f * 1024 + lane * 8];
      kf_[1] = *(const half8_t*)&Bse[f * 1024 + 512 + lane * 8];
      kf_[2] = *(const half8_t*)&Bse[4096 + f * 1024 + lane * 8];
      kf_[3] = *(const half8_t*)&Bse[4096 + f * 1024 + 512 + lane * 8];
      f32x4 s[4];
      if (dk < -128 || dk > 128) {
        float c = (dk < 0) ? b_lo : b_hi;
        #pragma unroll
        for (int qt = 0; qt < 4; ++qt) s[qt] = {c, c, c, c};
      } else {
        #pragma unroll
        for (int qt = 0; qt < 4; ++qt) {
          int dbase = dk + f * 16 + quad * 4 - qt * 16 - l16 + 192;
          #pragma unroll
          for (int r = 0; r < 4; ++r) s[qt][r] = biasl[dbase + r];
        }
      }
      __builtin_amdgcn_s_setprio(1);
      #pragma unroll
      for (int qt = 0; qt < 4; ++qt)
        #pragma unroll
        for (int kf = 0; kf < 4; ++kf)
          s[qt] = mfma_qk(kf_[kf], qf[kf][qt], s[qt]);
      __builtin_amdgcn_s_setprio(0);
      #pragma unroll
      for (int qt = 0; qt < 4; ++qt) {
        float p0 = fexp2(s[qt][0]), p1 = fexp2(s[qt][1]);
        float p2 = fexp2(s[qt][2]), p3 = fexp2(s[qt][3]);
        lpart[qt] += (p0 + p1) + (p2 + p3);
        union { half2_t h2[2]; half4_t h4; } u;
        u.h2[0] = __builtin_bit_cast(half2_t, __builtin_amdgcn_cvt_pkrtz(p0, p1));
        u.h2[1] = __builtin_bit_cast(half2_t, __builtin_amdgcn_cvt_pkrtz(p2, p3));
        if (j) pc[qt].p.hi = u.h4; else pc[qt].p.lo = u.h4;
      }
    }
    __builtin_amdgcn_s_setprio(1);
    #pragma unroll
    for (int d = 0; d < 4; ++d) {
      half8_t vc = *(const half8_t*)&Bse[8192 + (kw * 4 + d) * 512 + lane * 8];
      #pragma unroll
      for (int qt = 0; qt < 4; ++qt)
        oa[d][qt] = mfma_qk(vc, pc[qt].h8, oa[d][qt]);
    }
    __builtin_amdgcn_s_setprio(0);
    __syncthreads();   // staged t+1 landed; buffer t free for t+2
  }

  // ---- cross-half combine (kw=1 -> LDS, kw=0 adds + stores), 2 d-rounds ----
  #pragma unroll
  for (int qt = 0; qt < 4; ++qt) {
    lpart[qt] += __shfl_xor(lpart[qt], 16, 64);
    lpart[qt] += __shfl_xor(lpart[qt], 32, 64);
  }
  if (kw == 1) {
    if (quad == 0) {
      #pragma unroll
      for (int qt = 0; qt < 4; ++qt) lred[qw * 64 + qt * 16 + l16] = lpart[qt];
    }
    #pragma unroll
    for (int d = 0; d < 2; ++d)
      #pragma unroll
      for (int qt = 0; qt < 4; ++qt)
        *(f32x4*)&ored[(qw * 64 + qt * 16 + l16) * 36 + d * 16 + quad * 4] = oa[d][qt];
  }
  __syncthreads();
  float inv[4];
  if (kw == 0) {
    #pragma unroll
    for (int qt = 0; qt < 4; ++qt)
      inv[qt] = 1.f / (lpart[qt] + lred[qw * 64 + qt * 16 + l16]);
    #pragma unroll
    for (int d = 0; d < 2; ++d)
      #pragma unroll
      for (int qt = 0; qt < 4; ++qt) {
        f32x4 p = *(const f32x4*)&ored[(qw * 64 + qt * 16 + l16) * 36 + d * 16 + quad * 4];
        f32x4 sum = oa[d][qt] + p;
        sum[0] *= inv[qt]; sum[1] *= inv[qt]; sum[2] *= inv[qt]; sum[3] *= inv[qt];
        *(f32x4*)(out + (size_t)(b * S_LEN + qbase + qt * 16 + l16) * 1024 +
                  h * 64 + d * 16 + quad * 4) = sum;
      }
  }
  __syncthreads();
  if (kw == 1) {
    #pragma unroll
    for (int d = 2; d < 4; ++d)
      #pragma unroll
      for (int qt = 0; qt < 4; ++qt)
        *(f32x4*)&ored[(qw * 64 + qt * 16 + l16) * 36 + (d - 2) * 16 + quad * 4] = oa[d][qt];
  }
  __syncthreads();
  if (kw == 0) {
    #pragma unroll
    for (int d = 2; d < 4; ++d)
      #pragma unroll
      for (int qt = 0; qt < 4; ++qt) {
        f32x4 p = *(const f32x4*)&ored[(qw * 64 + qt * 16 + l16) * 36 + (d - 2) * 16 + quad * 4];
        f32x4 sum = oa[d][qt] + p;
        sum[0] *= inv[qt]; sum[1] *= inv[qt]; sum[2] *= inv[qt]; sum[3] *= inv[qt];
        *(f32x4*)(out + (size_t)(b * S_LEN + qbase + qt * 16 + l16) * 1024 +
                  h * 64 + d * 16 + quad * 4) = sum;
      }
  }
}

extern "C" void kernel_launch(void* const* d_in, const int* in_sizes, int n_in,
                              void* d_out, int out_size, void* d_ws, size_t ws_size,
                              hipStream_t stream) {
  (void)in_sizes; (void)n_in; (void)out_size; (void)ws_size;
  const float* x          = (const float*)d_in[0];
  const float* pos_embed  = (const float*)d_in[1];
  const float* W_pos_kq   = (const float*)d_in[2];
  const float* W_tok_kqv  = (const float*)d_in[3];
  const float* bias_table = (const float*)d_in[4];
  float* out = (float*)d_out;

  _Float16* ws = (_Float16*)d_ws;
  _Float16* pos_f  = ws;                     // 2,097,152
  _Float16* wt_pos = ws + 2097152;           // 2,097,152
  _Float16* x_f    = ws + 4194304;           // 4,194,304
  _Float16* wt_tok = ws + 8388608;           // 3,145,728
  _Float16* KG     = ws + 11534336;          // 4,194,304
  _Float16* KGP    = ws + 15728640;          // 2,097,152
  _Float16* VG     = ws + 17825792;          // 4,194,304
  _Float16* QRt    = ws + 22020096;          // 4,194,304
  _Float16* QRp    = ws + 26214400;          // 2,097,152
  // total 28,311,552 halfs = 56.6 MB

  const float QSCALE = 0.08838834764831845f * LOG2E;  // 1/sqrt(2*64) * log2e

  prep_kernel<<<7424, 256, 0, stream>>>(x, pos_embed, W_pos_kq, W_tok_kqv,
                                        x_f, pos_f, wt_pos, wt_tok);
  gemm_all_kernel<<<1024, 256, 0, stream>>>(pos_f, wt_pos, x_f, wt_tok,
                                            KGP, QRp, KG, QRt, VG, QSCALE);
  flash_kernel<<<256, 512, 0, stream>>>(QRt, QRp, KG, KGP, VG, bias_table, out);
}

// Round 9
// 194.816 us; speedup vs baseline: 1.0329x; 1.0329x over previous
//
#include <hip/hip_runtime.h>

#define S_LEN 2048
#define NH 16
#define LOG2E 1.4426950408889634f

typedef _Float16 half8_t __attribute__((ext_vector_type(8)));
typedef _Float16 half4_t __attribute__((ext_vector_type(4)));
typedef _Float16 half2_t __attribute__((ext_vector_type(2)));
typedef float f32x4 __attribute__((ext_vector_type(4)));

__device__ __forceinline__ f32x4 mfma_qk(half8_t a, half8_t b, f32x4 c) {
  return __builtin_amdgcn_mfma_f32_16x16x32_f16(a, b, c, 0, 0, 0);
}
__device__ __forceinline__ void glds16(const void* g, void* l) {
  __builtin_amdgcn_global_load_lds(
      (const __attribute__((address_space(1))) unsigned int*)g,
      (__attribute__((address_space(3))) unsigned int*)l, 16, 0, 0);
}
__device__ __forceinline__ float fexp2(float x) {
#if __has_builtin(__builtin_amdgcn_exp2f)
  return __builtin_amdgcn_exp2f(x);   // raw v_exp_f32, 1 instr
#else
  return exp2f(x);
#endif
}

// ---------------- fused prep: fp32->fp16 cvts + both weight transposes ----------
__global__ __launch_bounds__(256) void prep_kernel(const float* __restrict__ x,
                                                   const float* __restrict__ pos_embed,
                                                   const float* __restrict__ W_pos,
                                                   const float* __restrict__ W_tok,
                                                   _Float16* __restrict__ x_f,
                                                   _Float16* __restrict__ pos_f,
                                                   _Float16* __restrict__ wt_pos,
                                                   _Float16* __restrict__ wt_tok) {
  __shared__ float tile[64][65];
  const int bid = blockIdx.x, tid = threadIdx.x;
  if (bid < 6144) {
    // elementwise cvt: 1,572,864 float4 total (pos_embed first 524288, then x)
    int id = bid * 256 + tid;
    const float* src; _Float16* dst;
    if (id < 524288) { src = pos_embed; dst = pos_f; }
    else { id -= 524288; src = x; dst = x_f; }
    float4 f = ((const float4*)src)[id];
    half4_t o = {(_Float16)f.x, (_Float16)f.y, (_Float16)f.z, (_Float16)f.w};
    ((half4_t*)dst)[id] = o;
    return;
  }
  // weight transpose fp32 [K,N] -> fp16 [N,K], K=1024
  const float* W; _Float16* Wt; int N, nx, ky;
  if (bid < 6656) { W = W_pos; Wt = wt_pos; N = 2048; int t = bid - 6144; nx = t & 31; ky = t >> 5; }
  else            { W = W_tok; Wt = wt_tok; N = 3072; int t = bid - 6656; nx = t % 48; ky = t / 48; }
  int k0 = ky * 64, n0 = nx * 64;
  int tx = tid & 63, ty = tid >> 6;
  for (int j = 0; j < 16; ++j) {
    int k = ty * 16 + j;
    tile[k][tx] = W[(size_t)(k0 + k) * N + n0 + tx];
  }
  __syncthreads();
  for (int j = 0; j < 16; ++j) {
    int n = ty * 16 + j;
    Wt[(size_t)(n0 + n) * 1024 + k0 + tx] = (_Float16)tile[tx][n];
  }
}

// ---------------- merged fp16 GEMM (pos + tok), fragment-layout epilogues ------
// blocks [0,256):   pos gemm  2048x2048, A=pos_f, Bt=wt_pos, kg=KGP, qr=QRp
// blocks [256,1024): tok gemm 4096x3072, A=x_f,  Bt=wt_tok, kg=KG,  qr=QRt, vg=VG
// 2-phase double-buffered K-loop (R7-verified). V epilogue writes the
// PAIR-INTERLEAVED layout (R8-verified): feeds flash's K=32 PV fusion.
__global__ __launch_bounds__(256) void gemm_all_kernel(const _Float16* __restrict__ pos_f,
                                                       const _Float16* __restrict__ wt_pos,
                                                       const _Float16* __restrict__ x_f,
                                                       const _Float16* __restrict__ wt_tok,
                                                       _Float16* __restrict__ KGP,
                                                       _Float16* __restrict__ QRp,
                                                       _Float16* __restrict__ KG,
                                                       _Float16* __restrict__ QRt,
                                                       _Float16* __restrict__ VG,
                                                       float qscale) {
  __shared__ _Float16 SMem[16384];       // 32 KB: 2x (Ald|Bld) double-buffer
  _Float16* buf0 = SMem;                 // [0,4096)=A  [4096,8192)=B
  _Float16* buf1 = SMem + 8192;

  const int bid = blockIdx.x, tid = threadIdx.x;
  const _Float16 *A, *Bt; _Float16 *kg, *qr, *vg;
  int m0, n0;
  if (bid < 256) {
    A = pos_f; Bt = wt_pos; kg = KGP; qr = QRp; vg = nullptr;
    m0 = (bid >> 4) * 128; n0 = (bid & 15) * 128;
  } else {
    int t = bid - 256;
    A = x_f; Bt = wt_tok; kg = KG; qr = QRt; vg = VG;
    m0 = (t / 24) * 128; n0 = (t % 24) * 128;
  }
  const int K = 1024;

  const int wave = tid >> 6, lane = tid & 63;
  const int quad = lane >> 4, l16 = lane & 15;
  const int wm = (wave >> 1) * 64, wn = (wave & 1) * 64;

  f32x4 acc[4][4] = {};
  const int flat0 = tid, flat1 = tid + 256;
  const int r0 = flat0 >> 2, c0 = flat0 & 3;
  const int r1 = flat1 >> 2, c1 = flat1 & 3;

  auto stage = [&](int ko, _Float16* buf) {
    glds16(A + (size_t)(m0 + r0) * K + ko + c0 * 8, &buf[flat0 * 8]);
    glds16(Bt + (size_t)(n0 + r0) * K + ko + c0 * 8, &buf[4096 + flat0 * 8]);
    glds16(A + (size_t)(m0 + r1) * K + ko + c1 * 8, &buf[flat1 * 8]);
    glds16(Bt + (size_t)(n0 + r1) * K + ko + c1 * 8, &buf[4096 + flat1 * 8]);
  };
  auto kstep = [&](const _Float16* buf) {
    half8_t af[4], bfv[4];
    #pragma unroll
    for (int t = 0; t < 4; ++t) {
      af[t]  = *(const half8_t*)&buf[(wm + t * 16 + l16) * 32 + quad * 8];
      bfv[t] = *(const half8_t*)&buf[4096 + (wn + t * 16 + l16) * 32 + quad * 8];
    }
    #pragma unroll
    for (int mi = 0; mi < 4; ++mi)
      #pragma unroll
      for (int ni = 0; ni < 4; ++ni)
        acc[mi][ni] = mfma_qk(af[mi], bfv[ni], acc[mi][ni]);
  };

  stage(0, buf0);
  __syncthreads();
  #pragma unroll 1
  for (int ko = 0; ko < K; ko += 64) {
    stage(ko + 32, buf1);                 // next tile issues before compute
    kstep(buf0);
    __syncthreads();                      // readers done + buf1 loads landed
    if (ko + 64 < K) stage(ko + 64, buf0);
    kstep(buf1);
    __syncthreads();
  }
  // last barrier above also protects SMem before epilogue scratch reuse

  const int n_base = n0 + wn, m_base = m0 + wm;   // both 64-aligned
  const int bb = m_base >> 11;
  const int tile16 = (m_base & 2047) >> 6;

  if (n_base >= 2048) {
    // V region (tok only), pair-interleaved:
    // idx = ((mi>>1)*4 + ni)*512 + quad*128 + l16*8 + (mi&1)*4
    int hh = (n_base >> 6) & 15;
    _Float16* dstb = vg + (size_t)((bb * 16 + hh) * 32 + tile16) * 4096;
    #pragma unroll
    for (int mi = 0; mi < 4; ++mi)
      #pragma unroll
      for (int ni = 0; ni < 4; ++ni) {
        union { ushort4 u; _Float16 h[4]; } pk;
        #pragma unroll
        for (int r = 0; r < 4; ++r) pk.h[r] = (_Float16)acc[mi][ni][r];
        *(ushort4*)(dstb + ((mi >> 1) * 4 + ni) * 512 + quad * 128 + l16 * 8 +
                    (mi & 1) * 4) = pk.u;
      }
  } else if (n_base >= 1024) {
    // Q region: row-major, scaled
    #pragma unroll
    for (int mi = 0; mi < 4; ++mi)
      #pragma unroll
      for (int ni = 0; ni < 4; ++ni)
        #pragma unroll
        for (int r = 0; r < 4; ++r) {
          int m = m_base + mi * 16 + quad * 4 + r;
          int col = n_base - 1024 + ni * 16 + l16;
          qr[(size_t)m * 1024 + col] = (_Float16)(acc[mi][ni][r] * qscale);
        }
  } else {
    // K region: in-lane dim-transpose, 2 rounds of 32 keys through 4 KB/wave scratch
    int hh = n_base >> 6;
    int bhk = vg ? (bb * 16 + hh) : hh;
    _Float16* dstb = kg + (size_t)(bhk * 32 + tile16) * 4096;
    _Float16* Tr = SMem + wave * 2048;       // per-wave private 4 KB
    #pragma unroll
    for (int p = 0; p < 2; ++p) {
      #pragma unroll
      for (int mi2 = 0; mi2 < 2; ++mi2) {
        int mi = p * 2 + mi2;
        #pragma unroll
        for (int ni = 0; ni < 4; ++ni)
          #pragma unroll
          for (int r = 0; r < 4; ++r) {
            int keyp = mi2 * 16 + quad * 4 + r;            // 0..31
            int dim = ni * 16 + l16;
            int col = (((dim >> 3) ^ (keyp & 7)) << 3) | (dim & 7);
            Tr[keyp * 64 + col] = (_Float16)acc[mi][ni][r];
          }
      }
      #pragma unroll
      for (int j = 0; j < 4; ++j) {
        int wkp = j >> 1, kfl = j & 1;
        int wk = p * 2 + wkp;
        half8_t v = *(const half8_t*)&Tr[(wkp * 16 + l16) * 64 +
                                         (((kfl * 4 + quad) ^ (l16 & 7)) << 3)];
        *(half8_t*)(dstb + wk * 1024 + kfl * 512 + quad * 128 + l16 * 8) = v;
      }
    }
  }
}

// ---------------- fused flash attention v11: 8-wave LDS K/V, batched tile body ----
// v10 structure (R8-verified: 256 q-rows/block, grid 256, LDS-dbuf K/V, K=32
// PV fusion, no spill) with the tile body re-ordered for ILP: all 12 LDS b128
// reads up front, all 32 QK MFMAs as one cluster, then both exp batches, then
// PV. exp(j0) now overlaps QK(j1) issue instead of serializing between MFMA
// clusters. Same fp op order on lpart (bit-identical result). +~32 VGPR for
// dual score sets -- fits (R8 base was 108+64; budget 256). Guard: WRITE=16.4MB.
__global__ __launch_bounds__(512, 2) void flash_kernel(const _Float16* __restrict__ QRt,
                                                       const _Float16* __restrict__ QRp,
                                                       const _Float16* __restrict__ KG,
                                                       const _Float16* __restrict__ KGP,
                                                       const _Float16* __restrict__ VG,
                                                       const float* __restrict__ bias_table,
                                                       float* __restrict__ out) {
  __shared__ __align__(16) unsigned char SM[51712];
  _Float16* SK = (_Float16*)SM;             // [2][12288] halfs: Ktok|Kpos|V dbuf
  float* ored  = (float*)SM;                // [4][64][36] fp32, overlay after loop
  float* biasl = (float*)(SM + 49152);      // 384 floats
  float* lred  = (float*)(SM + 50688);      // [4][64] floats

  const int tid = threadIdx.x;
  const int wave = tid >> 6, lane = tid & 63;
  const int quad = lane >> 4, l16 = lane & 15;
  const int qw = wave & 3, kw = wave >> 2;
  const int lbid = blockIdx.x;
  const int q0 = ((lbid >> 3) & 7) * 256;        // 8 q-blocks per bh
  const int bh = (lbid & 7) + 8 * (lbid >> 6);   // bh's q-blocks share one XCD
  const int b = bh >> 4, h = bh & 15;

  if (tid < 384) {
    int i = tid;
    int delta = i - 192;
    int n = -delta;
    int ret = (n < 0) ? 16 : 0;
    int na = (n < 0) ? -n : n;
    int bkt;
    if (na < 8) bkt = na;
    else {
      int s2 = (na >= 12) + (na >= 16) + (na >= 23) + (na >= 32) +
               (na >= 46) + (na >= 64) + (na >= 91) + (na >= 128);
      bkt = 8 + s2; if (bkt > 15) bkt = 15;
    }
    bkt += ret;
    biasl[i] = bias_table[(size_t)(2048 + bkt) * NH + h] * LOG2E;
  }
  const float b_lo = bias_table[(2048 + 15) * NH + h] * LOG2E;
  const float b_hi = bias_table[(2048 + 31) * NH + h] * LOG2E;

  // Q fragments (pre-scaled in gemm epilogue); wave's rows = q0+qw*64+qt*16+l16
  const int qbase = q0 + qw * 64;
  half8_t qf[4][4];
  {
    const _Float16* tq = QRt + (size_t)(b * S_LEN + qbase + l16) * 1024 + h * 64 + quad * 8;
    const _Float16* pq = QRp + (size_t)(qbase + l16) * 1024 + h * 64 + quad * 8;
    #pragma unroll
    for (int qt = 0; qt < 4; ++qt)
      #pragma unroll
      for (int kf = 0; kf < 2; ++kf) {
        qf[kf][qt]     = *(const half8_t*)(tq + (size_t)qt * 16 * 1024 + kf * 32);
        qf[kf + 2][qt] = *(const half8_t*)(pq + (size_t)qt * 16 * 1024 + kf * 32);
      }
  }

  const _Float16* kgp = KG  + (size_t)bh * 131072;
  const _Float16* kpp = KGP + (size_t)h  * 131072;
  const _Float16* vgp = VG  + (size_t)bh * 131072;

  auto stage = [&](int t, int par) {
    _Float16* dst = SK + par * 12288;
    glds16(kgp + (size_t)t * 4096 + tid * 8, dst + tid * 8);
    glds16(kpp + (size_t)t * 4096 + tid * 8, dst + 4096 + tid * 8);
    glds16(vgp + (size_t)t * 4096 + tid * 8, dst + 8192 + tid * 8);
  };

  f32x4 oa[4][4] = {};
  float lpart[4] = {0.f, 0.f, 0.f, 0.f};
  union VP8 { half8_t h8; struct { half4_t lo, hi; } p; };

  stage(0, 0);
  __syncthreads();   // also covers biasl

  #pragma unroll 1
  for (int t = 0; t < 32; ++t) {
    if (t != 31) stage(t + 1, (t + 1) & 1);
    const _Float16* Bse = SK + (t & 1) * 12288;
    const int dk = t * 64 - q0 - qw * 64;   // 64-granular
    const int f0 = kw * 2;

    // ---- all LDS reads up front (12x b128) ----
    half8_t kf0[4], kf1[4], vc[4];
    kf0[0] = *(const half8_t*)&Bse[f0 * 1024 + lane * 8];
    kf0[1] = *(const half8_t*)&Bse[f0 * 1024 + 512 + lane * 8];
    kf0[2] = *(const half8_t*)&Bse[4096 + f0 * 1024 + lane * 8];
    kf0[3] = *(const half8_t*)&Bse[4096 + f0 * 1024 + 512 + lane * 8];
    kf1[0] = *(const half8_t*)&Bse[(f0 + 1) * 1024 + lane * 8];
    kf1[1] = *(const half8_t*)&Bse[(f0 + 1) * 1024 + 512 + lane * 8];
    kf1[2] = *(const half8_t*)&Bse[4096 + (f0 + 1) * 1024 + lane * 8];
    kf1[3] = *(const half8_t*)&Bse[4096 + (f0 + 1) * 1024 + 512 + lane * 8];
    #pragma unroll
    for (int d = 0; d < 4; ++d)
      vc[d] = *(const half8_t*)&Bse[8192 + (kw * 4 + d) * 512 + lane * 8];

    // ---- bias init for both sub-tiles ----
    f32x4 s0[4], s1[4];
    if (dk < -128 || dk > 128) {
      float c = (dk < 0) ? b_lo : b_hi;
      #pragma unroll
      for (int qt = 0; qt < 4; ++qt) { s0[qt] = {c, c, c, c}; s1[qt] = {c, c, c, c}; }
    } else {
      #pragma unroll
      for (int qt = 0; qt < 4; ++qt) {
        int dbase = dk + f0 * 16 + quad * 4 - qt * 16 - l16 + 192;
        #pragma unroll
        for (int r = 0; r < 4; ++r) s0[qt][r] = biasl[dbase + r];
        #pragma unroll
        for (int r = 0; r < 4; ++r) s1[qt][r] = biasl[dbase + 16 + r];
      }
    }

    // ---- 32 QK MFMAs, one cluster ----
    __builtin_amdgcn_s_setprio(1);
    #pragma unroll
    for (int qt = 0; qt < 4; ++qt)
      #pragma unroll
      for (int kf = 0; kf < 4; ++kf)
        s0[qt] = mfma_qk(kf0[kf], qf[kf][qt], s0[qt]);
    #pragma unroll
    for (int qt = 0; qt < 4; ++qt)
      #pragma unroll
      for (int kf = 0; kf < 4; ++kf)
        s1[qt] = mfma_qk(kf1[kf], qf[kf][qt], s1[qt]);
    __builtin_amdgcn_s_setprio(0);

    // ---- exp both sub-tiles (same lpart fp order as v10) ----
    VP8 pc[4];
    #pragma unroll
    for (int qt = 0; qt < 4; ++qt) {
      float p0 = fexp2(s0[qt][0]), p1 = fexp2(s0[qt][1]);
      float p2 = fexp2(s0[qt][2]), p3 = fexp2(s0[qt][3]);
      lpart[qt] += (p0 + p1) + (p2 + p3);
      union { half2_t h2[2]; half4_t h4; } u;
      u.h2[0] = __builtin_bit_cast(half2_t, __builtin_amdgcn_cvt_pkrtz(p0, p1));
      u.h2[1] = __builtin_bit_cast(half2_t, __builtin_amdgcn_cvt_pkrtz(p2, p3));
      pc[qt].p.lo = u.h4;
    }
    #pragma unroll
    for (int qt = 0; qt < 4; ++qt) {
      float p0 = fexp2(s1[qt][0]), p1 = fexp2(s1[qt][1]);
      float p2 = fexp2(s1[qt][2]), p3 = fexp2(s1[qt][3]);
      lpart[qt] += (p0 + p1) + (p2 + p3);
      union { half2_t h2[2]; half4_t h4; } u;
      u.h2[0] = __builtin_bit_cast(half2_t, __builtin_amdgcn_cvt_pkrtz(p0, p1));
      u.h2[1] = __builtin_bit_cast(half2_t, __builtin_amdgcn_cvt_pkrtz(p2, p3));
      pc[qt].p.hi = u.h4;
    }

    // ---- PV ----
    __builtin_amdgcn_s_setprio(1);
    #pragma unroll
    for (int d = 0; d < 4; ++d)
      #pragma unroll
      for (int qt = 0; qt < 4; ++qt)
        oa[d][qt] = mfma_qk(vc[d], pc[qt].h8, oa[d][qt]);
    __builtin_amdgcn_s_setprio(0);
    __syncthreads();   // staged t+1 landed; buffer t free for t+2
  }

  // ---- cross-half combine (kw=1 -> LDS, kw=0 adds + stores), 2 d-rounds ----
  #pragma unroll
  for (int qt = 0; qt < 4; ++qt) {
    lpart[qt] += __shfl_xor(lpart[qt], 16, 64);
    lpart[qt] += __shfl_xor(lpart[qt], 32, 64);
  }
  if (kw == 1) {
    if (quad == 0) {
      #pragma unroll
      for (int qt = 0; qt < 4; ++qt) lred[qw * 64 + qt * 16 + l16] = lpart[qt];
    }
    #pragma unroll
    for (int d = 0; d < 2; ++d)
      #pragma unroll
      for (int qt = 0; qt < 4; ++qt)
        *(f32x4*)&ored[(qw * 64 + qt * 16 + l16) * 36 + d * 16 + quad * 4] = oa[d][qt];
  }
  __syncthreads();
  float inv[4];
  if (kw == 0) {
    #pragma unroll
    for (int qt = 0; qt < 4; ++qt)
      inv[qt] = 1.f / (lpart[qt] + lred[qw * 64 + qt * 16 + l16]);
    #pragma unroll
    for (int d = 0; d < 2; ++d)
      #pragma unroll
      for (int qt = 0; qt < 4; ++qt) {
        f32x4 p = *(const f32x4*)&ored[(qw * 64 + qt * 16 + l16) * 36 + d * 16 + quad * 4];
        f32x4 sum = oa[d][qt] + p;
        sum[0] *= inv[qt]; sum[1] *= inv[qt]; sum[2] *= inv[qt]; sum[3] *= inv[qt];
        *(f32x4*)(out + (size_t)(b * S_LEN + qbase + qt * 16 + l16) * 1024 +
                  h * 64 + d * 16 + quad * 4) = sum;
      }
  }
  __syncthreads();
  if (kw == 1) {
    #pragma unroll
    for (int d = 2; d < 4; ++d)
      #pragma unroll
      for (int qt = 0; qt < 4; ++qt)
        *(f32x4*)&ored[(qw * 64 + qt * 16 + l16) * 36 + (d - 2) * 16 + quad * 4] = oa[d][qt];
  }
  __syncthreads();
  if (kw == 0) {
    #pragma unroll
    for (int d = 2; d < 4; ++d)
      #pragma unroll
      for (int qt = 0; qt < 4; ++qt) {
        f32x4 p = *(const f32x4*)&ored[(qw * 64 + qt * 16 + l16) * 36 + (d - 2) * 16 + quad * 4];
        f32x4 sum = oa[d][qt] + p;
        sum[0] *= inv[qt]; sum[1] *= inv[qt]; sum[2] *= inv[qt]; sum[3] *= inv[qt];
        *(f32x4*)(out + (size_t)(b * S_LEN + qbase + qt * 16 + l16) * 1024 +
                  h * 64 + (d - 2) * 16 + quad * 4 + 32) = sum;
      }
  }
}

extern "C" void kernel_launch(void* const* d_in, const int* in_sizes, int n_in,
                              void* d_out, int out_size, void* d_ws, size_t ws_size,
                              hipStream_t stream) {
  (void)in_sizes; (void)n_in; (void)out_size; (void)ws_size;
  const float* x          = (const float*)d_in[0];
  const float* pos_embed  = (const float*)d_in[1];
  const float* W_pos_kq   = (const float*)d_in[2];
  const float* W_tok_kqv  = (const float*)d_in[3];
  const float* bias_table = (const float*)d_in[4];
  float* out = (float*)d_out;

  _Float16* ws = (_Float16*)d_ws;
  _Float16* pos_f  = ws;                     // 2,097,152
  _Float16* wt_pos = ws + 2097152;           // 2,097,152
  _Float16* x_f    = ws + 4194304;           // 4,194,304
  _Float16* wt_tok = ws + 8388608;           // 3,145,728
  _Float16* KG     = ws + 11534336;          // 4,194,304
  _Float16* KGP    = ws + 15728640;          // 2,097,152
  _Float16* VG     = ws + 17825792;          // 4,194,304
  _Float16* QRt    = ws + 22020096;          // 4,194,304
  _Float16* QRp    = ws + 26214400;          // 2,097,152
  // total 28,311,552 halfs = 56.6 MB

  const float QSCALE = 0.08838834764831845f * LOG2E;  // 1/sqrt(2*64) * log2e

  prep_kernel<<<7424, 256, 0, stream>>>(x, pos_embed, W_pos_kq, W_tok_kqv,
                                        x_f, pos_f, wt_pos, wt_tok);
  gemm_all_kernel<<<1024, 256, 0, stream>>>(pos_f, wt_pos, x_f, wt_tok,
                                            KGP, QRp, KG, QRt, VG, QSCALE);
  flash_kernel<<<256, 512, 0, stream>>>(QRt, QRp, KG, KGP, VG, bias_table, out);
}

// Round 10
// 193.402 us; speedup vs baseline: 1.0404x; 1.0073x over previous
//
#include <hip/hip_runtime.h>

#define S_LEN 2048
#define NH 16
#define LOG2E 1.4426950408889634f

typedef _Float16 half8_t __attribute__((ext_vector_type(8)));
typedef _Float16 half4_t __attribute__((ext_vector_type(4)));
typedef _Float16 half2_t __attribute__((ext_vector_type(2)));
typedef float f32x4 __attribute__((ext_vector_type(4)));

__device__ __forceinline__ f32x4 mfma_qk(half8_t a, half8_t b, f32x4 c) {
  return __builtin_amdgcn_mfma_f32_16x16x32_f16(a, b, c, 0, 0, 0);
}
__device__ __forceinline__ void glds16(const void* g, void* l) {
  __builtin_amdgcn_global_load_lds(
      (const __attribute__((address_space(1))) unsigned int*)g,
      (__attribute__((address_space(3))) unsigned int*)l, 16, 0, 0);
}
__device__ __forceinline__ float fexp2(float x) {
#if __has_builtin(__builtin_amdgcn_exp2f)
  return __builtin_amdgcn_exp2f(x);   // raw v_exp_f32, 1 instr
#else
  return exp2f(x);
#endif
}

// ---------------- fused prep: fp32->fp16 cvts + both weight transposes ----------
__global__ __launch_bounds__(256) void prep_kernel(const float* __restrict__ x,
                                                   const float* __restrict__ pos_embed,
                                                   const float* __restrict__ W_pos,
                                                   const float* __restrict__ W_tok,
                                                   _Float16* __restrict__ x_f,
                                                   _Float16* __restrict__ pos_f,
                                                   _Float16* __restrict__ wt_pos,
                                                   _Float16* __restrict__ wt_tok) {
  __shared__ float tile[64][65];
  const int bid = blockIdx.x, tid = threadIdx.x;
  if (bid < 6144) {
    // elementwise cvt: 1,572,864 float4 total (pos_embed first 524288, then x)
    int id = bid * 256 + tid;
    const float* src; _Float16* dst;
    if (id < 524288) { src = pos_embed; dst = pos_f; }
    else { id -= 524288; src = x; dst = x_f; }
    float4 f = ((const float4*)src)[id];
    half4_t o = {(_Float16)f.x, (_Float16)f.y, (_Float16)f.z, (_Float16)f.w};
    ((half4_t*)dst)[id] = o;
    return;
  }
  // weight transpose fp32 [K,N] -> fp16 [N,K], K=1024
  const float* W; _Float16* Wt; int N, nx, ky;
  if (bid < 6656) { W = W_pos; Wt = wt_pos; N = 2048; int t = bid - 6144; nx = t & 31; ky = t >> 5; }
  else            { W = W_tok; Wt = wt_tok; N = 3072; int t = bid - 6656; nx = t % 48; ky = t / 48; }
  int k0 = ky * 64, n0 = nx * 64;
  int tx = tid & 63, ty = tid >> 6;
  for (int j = 0; j < 16; ++j) {
    int k = ty * 16 + j;
    tile[k][tx] = W[(size_t)(k0 + k) * N + n0 + tx];
  }
  __syncthreads();
  for (int j = 0; j < 16; ++j) {
    int n = ty * 16 + j;
    Wt[(size_t)(n0 + n) * 1024 + k0 + tx] = (_Float16)tile[tx][n];
  }
}

// ---------------- merged fp16 GEMM (pos + tok), fragment-layout epilogues ------
// blocks [0,256):   pos gemm  2048x2048, A=pos_f, Bt=wt_pos, kg=KGP, qr=QRp
// blocks [256,1024): tok gemm 4096x3072, A=x_f,  Bt=wt_tok, kg=KG,  qr=QRt, vg=VG
// 2-phase double-buffered K-loop (R7-verified). V epilogue writes the
// PAIR-INTERLEAVED layout (R8-verified): feeds flash's K=32 PV fusion.
__global__ __launch_bounds__(256) void gemm_all_kernel(const _Float16* __restrict__ pos_f,
                                                       const _Float16* __restrict__ wt_pos,
                                                       const _Float16* __restrict__ x_f,
                                                       const _Float16* __restrict__ wt_tok,
                                                       _Float16* __restrict__ KGP,
                                                       _Float16* __restrict__ QRp,
                                                       _Float16* __restrict__ KG,
                                                       _Float16* __restrict__ QRt,
                                                       _Float16* __restrict__ VG,
                                                       float qscale) {
  __shared__ _Float16 SMem[16384];       // 32 KB: 2x (Ald|Bld) double-buffer
  _Float16* buf0 = SMem;                 // [0,4096)=A  [4096,8192)=B
  _Float16* buf1 = SMem + 8192;

  const int bid = blockIdx.x, tid = threadIdx.x;
  const _Float16 *A, *Bt; _Float16 *kg, *qr, *vg;
  int m0, n0;
  if (bid < 256) {
    A = pos_f; Bt = wt_pos; kg = KGP; qr = QRp; vg = nullptr;
    m0 = (bid >> 4) * 128; n0 = (bid & 15) * 128;
  } else {
    int t = bid - 256;
    A = x_f; Bt = wt_tok; kg = KG; qr = QRt; vg = VG;
    m0 = (t / 24) * 128; n0 = (t % 24) * 128;
  }
  const int K = 1024;

  const int wave = tid >> 6, lane = tid & 63;
  const int quad = lane >> 4, l16 = lane & 15;
  const int wm = (wave >> 1) * 64, wn = (wave & 1) * 64;

  f32x4 acc[4][4] = {};
  const int flat0 = tid, flat1 = tid + 256;
  const int r0 = flat0 >> 2, c0 = flat0 & 3;
  const int r1 = flat1 >> 2, c1 = flat1 & 3;

  auto stage = [&](int ko, _Float16* buf) {
    glds16(A + (size_t)(m0 + r0) * K + ko + c0 * 8, &buf[flat0 * 8]);
    glds16(Bt + (size_t)(n0 + r0) * K + ko + c0 * 8, &buf[4096 + flat0 * 8]);
    glds16(A + (size_t)(m0 + r1) * K + ko + c1 * 8, &buf[flat1 * 8]);
    glds16(Bt + (size_t)(n0 + r1) * K + ko + c1 * 8, &buf[4096 + flat1 * 8]);
  };
  auto kstep = [&](const _Float16* buf) {
    half8_t af[4], bfv[4];
    #pragma unroll
    for (int t = 0; t < 4; ++t) {
      af[t]  = *(const half8_t*)&buf[(wm + t * 16 + l16) * 32 + quad * 8];
      bfv[t] = *(const half8_t*)&buf[4096 + (wn + t * 16 + l16) * 32 + quad * 8];
    }
    #pragma unroll
    for (int mi = 0; mi < 4; ++mi)
      #pragma unroll
      for (int ni = 0; ni < 4; ++ni)
        acc[mi][ni] = mfma_qk(af[mi], bfv[ni], acc[mi][ni]);
  };

  stage(0, buf0);
  __syncthreads();
  #pragma unroll 1
  for (int ko = 0; ko < K; ko += 64) {
    stage(ko + 32, buf1);                 // next tile issues before compute
    kstep(buf0);
    __syncthreads();                      // readers done + buf1 loads landed
    if (ko + 64 < K) stage(ko + 64, buf0);
    kstep(buf1);
    __syncthreads();
  }
  // last barrier above also protects SMem before epilogue scratch reuse

  const int n_base = n0 + wn, m_base = m0 + wm;   // both 64-aligned
  const int bb = m_base >> 11;
  const int tile16 = (m_base & 2047) >> 6;

  if (n_base >= 2048) {
    // V region (tok only), pair-interleaved:
    // idx = ((mi>>1)*4 + ni)*512 + quad*128 + l16*8 + (mi&1)*4
    int hh = (n_base >> 6) & 15;
    _Float16* dstb = vg + (size_t)((bb * 16 + hh) * 32 + tile16) * 4096;
    #pragma unroll
    for (int mi = 0; mi < 4; ++mi)
      #pragma unroll
      for (int ni = 0; ni < 4; ++ni) {
        union { ushort4 u; _Float16 h[4]; } pk;
        #pragma unroll
        for (int r = 0; r < 4; ++r) pk.h[r] = (_Float16)acc[mi][ni][r];
        *(ushort4*)(dstb + ((mi >> 1) * 4 + ni) * 512 + quad * 128 + l16 * 8 +
                    (mi & 1) * 4) = pk.u;
      }
  } else if (n_base >= 1024) {
    // Q region: row-major, scaled
    #pragma unroll
    for (int mi = 0; mi < 4; ++mi)
      #pragma unroll
      for (int ni = 0; ni < 4; ++ni)
        #pragma unroll
        for (int r = 0; r < 4; ++r) {
          int m = m_base + mi * 16 + quad * 4 + r;
          int col = n_base - 1024 + ni * 16 + l16;
          qr[(size_t)m * 1024 + col] = (_Float16)(acc[mi][ni][r] * qscale);
        }
  } else {
    // K region: in-lane dim-transpose, 2 rounds of 32 keys through 4 KB/wave scratch
    int hh = n_base >> 6;
    int bhk = vg ? (bb * 16 + hh) : hh;
    _Float16* dstb = kg + (size_t)(bhk * 32 + tile16) * 4096;
    _Float16* Tr = SMem + wave * 2048;       // per-wave private 4 KB
    #pragma unroll
    for (int p = 0; p < 2; ++p) {
      #pragma unroll
      for (int mi2 = 0; mi2 < 2; ++mi2) {
        int mi = p * 2 + mi2;
        #pragma unroll
        for (int ni = 0; ni < 4; ++ni)
          #pragma unroll
          for (int r = 0; r < 4; ++r) {
            int keyp = mi2 * 16 + quad * 4 + r;            // 0..31
            int dim = ni * 16 + l16;
            int col = (((dim >> 3) ^ (keyp & 7)) << 3) | (dim & 7);
            Tr[keyp * 64 + col] = (_Float16)acc[mi][ni][r];
          }
      }
      #pragma unroll
      for (int j = 0; j < 4; ++j) {
        int wkp = j >> 1, kfl = j & 1;
        int wk = p * 2 + wkp;
        half8_t v = *(const half8_t*)&Tr[(wkp * 16 + l16) * 64 +
                                         (((kfl * 4 + quad) ^ (l16 & 7)) << 3)];
        *(half8_t*)(dstb + wk * 1024 + kfl * 512 + quad * 128 + l16 * 8) = v;
      }
    }
  }
}

// ---------------- fused flash attention v12: pair-deep staging, barrier per 2 tiles
// v11 tile body verbatim (R9-verified: batched reads -> 32-QK cluster -> exp ->
// PV, no spill). Change: 4 LDS tile-buffers (2 pairs), stage pair p+1 at pair
// top, ONE barrier per pair (16 total vs 32). Within a pair the two tile
// bodies have no barrier: scheduler can hoist tile-b reads/QK under tile-a PV,
// and the 2 waves/SIMD can drift anti-phase so exp (VALU/trans) overlaps the
// other wave's MFMA. LDS 100.9 KB static (1 block/CU; hardware 160 KB).
__global__ __launch_bounds__(512, 1) void flash_kernel(const _Float16* __restrict__ QRt,
                                                       const _Float16* __restrict__ QRp,
                                                       const _Float16* __restrict__ KG,
                                                       const _Float16* __restrict__ KGP,
                                                       const _Float16* __restrict__ VG,
                                                       const float* __restrict__ bias_table,
                                                       float* __restrict__ out) {
  __shared__ __align__(16) unsigned char SM[100864];
  _Float16* SK = (_Float16*)SM;             // [4][12288] halfs: Ktok|Kpos|V, 4 tile-buffers
  float* ored  = (float*)SM;                // [4][64][36] fp32, overlay after loop
  float* biasl = (float*)(SM + 98304);      // 384 floats
  float* lred  = (float*)(SM + 99840);      // [4][64] floats

  const int tid = threadIdx.x;
  const int wave = tid >> 6, lane = tid & 63;
  const int quad = lane >> 4, l16 = lane & 15;
  const int qw = wave & 3, kw = wave >> 2;
  const int lbid = blockIdx.x;
  const int q0 = ((lbid >> 3) & 7) * 256;        // 8 q-blocks per bh
  const int bh = (lbid & 7) + 8 * (lbid >> 6);   // bh's q-blocks share one XCD
  const int b = bh >> 4, h = bh & 15;

  if (tid < 384) {
    int i = tid;
    int delta = i - 192;
    int n = -delta;
    int ret = (n < 0) ? 16 : 0;
    int na = (n < 0) ? -n : n;
    int bkt;
    if (na < 8) bkt = na;
    else {
      int s2 = (na >= 12) + (na >= 16) + (na >= 23) + (na >= 32) +
               (na >= 46) + (na >= 64) + (na >= 91) + (na >= 128);
      bkt = 8 + s2; if (bkt > 15) bkt = 15;
    }
    bkt += ret;
    biasl[i] = bias_table[(size_t)(2048 + bkt) * NH + h] * LOG2E;
  }
  const float b_lo = bias_table[(2048 + 15) * NH + h] * LOG2E;
  const float b_hi = bias_table[(2048 + 31) * NH + h] * LOG2E;

  // Q fragments (pre-scaled in gemm epilogue); wave's rows = q0+qw*64+qt*16+l16
  const int qbase = q0 + qw * 64;
  half8_t qf[4][4];
  {
    const _Float16* tq = QRt + (size_t)(b * S_LEN + qbase + l16) * 1024 + h * 64 + quad * 8;
    const _Float16* pq = QRp + (size_t)(qbase + l16) * 1024 + h * 64 + quad * 8;
    #pragma unroll
    for (int qt = 0; qt < 4; ++qt)
      #pragma unroll
      for (int kf = 0; kf < 2; ++kf) {
        qf[kf][qt]     = *(const half8_t*)(tq + (size_t)qt * 16 * 1024 + kf * 32);
        qf[kf + 2][qt] = *(const half8_t*)(pq + (size_t)qt * 16 * 1024 + kf * 32);
      }
  }

  const _Float16* kgp = KG  + (size_t)bh * 131072;
  const _Float16* kpp = KGP + (size_t)h  * 131072;
  const _Float16* vgp = VG  + (size_t)bh * 131072;

  auto stage = [&](int t, int buf) {
    _Float16* dst = SK + buf * 12288;
    glds16(kgp + (size_t)t * 4096 + tid * 8, dst + tid * 8);
    glds16(kpp + (size_t)t * 4096 + tid * 8, dst + 4096 + tid * 8);
    glds16(vgp + (size_t)t * 4096 + tid * 8, dst + 8192 + tid * 8);
  };

  f32x4 oa[4][4] = {};
  float lpart[4] = {0.f, 0.f, 0.f, 0.f};
  union VP8 { half8_t h8; struct { half4_t lo, hi; } p; };

  auto tile_body = [&](int t, const _Float16* Bse) {
    const int dk = t * 64 - q0 - qw * 64;   // 64-granular
    const int f0 = kw * 2;

    // ---- all LDS reads up front (12x b128) ----
    half8_t kf0[4], kf1[4], vc[4];
    kf0[0] = *(const half8_t*)&Bse[f0 * 1024 + lane * 8];
    kf0[1] = *(const half8_t*)&Bse[f0 * 1024 + 512 + lane * 8];
    kf0[2] = *(const half8_t*)&Bse[4096 + f0 * 1024 + lane * 8];
    kf0[3] = *(const half8_t*)&Bse[4096 + f0 * 1024 + 512 + lane * 8];
    kf1[0] = *(const half8_t*)&Bse[(f0 + 1) * 1024 + lane * 8];
    kf1[1] = *(const half8_t*)&Bse[(f0 + 1) * 1024 + 512 + lane * 8];
    kf1[2] = *(const half8_t*)&Bse[4096 + (f0 + 1) * 1024 + lane * 8];
    kf1[3] = *(const half8_t*)&Bse[4096 + (f0 + 1) * 1024 + 512 + lane * 8];
    #pragma unroll
    for (int d = 0; d < 4; ++d)
      vc[d] = *(const half8_t*)&Bse[8192 + (kw * 4 + d) * 512 + lane * 8];

    // ---- bias init for both sub-tiles ----
    f32x4 s0[4], s1[4];
    if (dk < -128 || dk > 128) {
      float c = (dk < 0) ? b_lo : b_hi;
      #pragma unroll
      for (int qt = 0; qt < 4; ++qt) { s0[qt] = {c, c, c, c}; s1[qt] = {c, c, c, c}; }
    } else {
      #pragma unroll
      for (int qt = 0; qt < 4; ++qt) {
        int dbase = dk + f0 * 16 + quad * 4 - qt * 16 - l16 + 192;
        #pragma unroll
        for (int r = 0; r < 4; ++r) s0[qt][r] = biasl[dbase + r];
        #pragma unroll
        for (int r = 0; r < 4; ++r) s1[qt][r] = biasl[dbase + 16 + r];
      }
    }

    // ---- 32 QK MFMAs, one cluster ----
    __builtin_amdgcn_s_setprio(1);
    #pragma unroll
    for (int qt = 0; qt < 4; ++qt)
      #pragma unroll
      for (int kf = 0; kf < 4; ++kf)
        s0[qt] = mfma_qk(kf0[kf], qf[kf][qt], s0[qt]);
    #pragma unroll
    for (int qt = 0; qt < 4; ++qt)
      #pragma unroll
      for (int kf = 0; kf < 4; ++kf)
        s1[qt] = mfma_qk(kf1[kf], qf[kf][qt], s1[qt]);
    __builtin_amdgcn_s_setprio(0);

    // ---- exp both sub-tiles (same lpart fp order) ----
    VP8 pc[4];
    #pragma unroll
    for (int qt = 0; qt < 4; ++qt) {
      float p0 = fexp2(s0[qt][0]), p1 = fexp2(s0[qt][1]);
      float p2 = fexp2(s0[qt][2]), p3 = fexp2(s0[qt][3]);
      lpart[qt] += (p0 + p1) + (p2 + p3);
      union { half2_t h2[2]; half4_t h4; } u;
      u.h2[0] = __builtin_bit_cast(half2_t, __builtin_amdgcn_cvt_pkrtz(p0, p1));
      u.h2[1] = __builtin_bit_cast(half2_t, __builtin_amdgcn_cvt_pkrtz(p2, p3));
      pc[qt].p.lo = u.h4;
    }
    #pragma unroll
    for (int qt = 0; qt < 4; ++qt) {
      float p0 = fexp2(s1[qt][0]), p1 = fexp2(s1[qt][1]);
      float p2 = fexp2(s1[qt][2]), p3 = fexp2(s1[qt][3]);
      lpart[qt] += (p0 + p1) + (p2 + p3);
      union { half2_t h2[2]; half4_t h4; } u;
      u.h2[0] = __builtin_bit_cast(half2_t, __builtin_amdgcn_cvt_pkrtz(p0, p1));
      u.h2[1] = __builtin_bit_cast(half2_t, __builtin_amdgcn_cvt_pkrtz(p2, p3));
      pc[qt].p.hi = u.h4;
    }

    // ---- PV ----
    __builtin_amdgcn_s_setprio(1);
    #pragma unroll
    for (int d = 0; d < 4; ++d)
      #pragma unroll
      for (int qt = 0; qt < 4; ++qt)
        oa[d][qt] = mfma_qk(vc[d], pc[qt].h8, oa[d][qt]);
    __builtin_amdgcn_s_setprio(0);
  };

  stage(0, 0); stage(1, 1);
  __syncthreads();   // also covers biasl

  #pragma unroll 1
  for (int p = 0; p < 16; ++p) {
    const int base = (p & 1) * 2;          // compute buffers {base, base+1}
    if (p != 15) { stage(2 * p + 2, base ^ 2); stage(2 * p + 3, (base ^ 2) + 1); }
    tile_body(2 * p,     SK + base * 12288);
    tile_body(2 * p + 1, SK + (base + 1) * 12288);
    __syncthreads();   // pair p+1 landed; buffers {base,base+1} free
  }

  // ---- cross-half combine (kw=1 -> LDS, kw=0 adds + stores), 2 d-rounds ----
  #pragma unroll
  for (int qt = 0; qt < 4; ++qt) {
    lpart[qt] += __shfl_xor(lpart[qt], 16, 64);
    lpart[qt] += __shfl_xor(lpart[qt], 32, 64);
  }
  if (kw == 1) {
    if (quad == 0) {
      #pragma unroll
      for (int qt = 0; qt < 4; ++qt) lred[qw * 64 + qt * 16 + l16] = lpart[qt];
    }
    #pragma unroll
    for (int d = 0; d < 2; ++d)
      #pragma unroll
      for (int qt = 0; qt < 4; ++qt)
        *(f32x4*)&ored[(qw * 64 + qt * 16 + l16) * 36 + d * 16 + quad * 4] = oa[d][qt];
  }
  __syncthreads();
  float inv[4];
  if (kw == 0) {
    #pragma unroll
    for (int qt = 0; qt < 4; ++qt)
      inv[qt] = 1.f / (lpart[qt] + lred[qw * 64 + qt * 16 + l16]);
    #pragma unroll
    for (int d = 0; d < 2; ++d)
      #pragma unroll
      for (int qt = 0; qt < 4; ++qt) {
        f32x4 p = *(const f32x4*)&ored[(qw * 64 + qt * 16 + l16) * 36 + d * 16 + quad * 4];
        f32x4 sum = oa[d][qt] + p;
        sum[0] *= inv[qt]; sum[1] *= inv[qt]; sum[2] *= inv[qt]; sum[3] *= inv[qt];
        *(f32x4*)(out + (size_t)(b * S_LEN + qbase + qt * 16 + l16) * 1024 +
                  h * 64 + d * 16 + quad * 4) = sum;
      }
  }
  __syncthreads();
  if (kw == 1) {
    #pragma unroll
    for (int d = 2; d < 4; ++d)
      #pragma unroll
      for (int qt = 0; qt < 4; ++qt)
        *(f32x4*)&ored[(qw * 64 + qt * 16 + l16) * 36 + (d - 2) * 16 + quad * 4] = oa[d][qt];
  }
  __syncthreads();
  if (kw == 0) {
    #pragma unroll
    for (int d = 2; d < 4; ++d)
      #pragma unroll
      for (int qt = 0; qt < 4; ++qt) {
        f32x4 p = *(const f32x4*)&ored[(qw * 64 + qt * 16 + l16) * 36 + (d - 2) * 16 + quad * 4];
        f32x4 sum = oa[d][qt] + p;
        sum[0] *= inv[qt]; sum[1] *= inv[qt]; sum[2] *= inv[qt]; sum[3] *= inv[qt];
        *(f32x4*)(out + (size_t)(b * S_LEN + qbase + qt * 16 + l16) * 1024 +
                  h * 64 + (d - 2) * 16 + quad * 4 + 32) = sum;
      }
  }
}

extern "C" void kernel_launch(void* const* d_in, const int* in_sizes, int n_in,
                              void* d_out, int out_size, void* d_ws, size_t ws_size,
                              hipStream_t stream) {
  (void)in_sizes; (void)n_in; (void)out_size; (void)ws_size;
  const float* x          = (const float*)d_in[0];
  const float* pos_embed  = (const float*)d_in[1];
  const float* W_pos_kq   = (const float*)d_in[2];
  const float* W_tok_kqv  = (const float*)d_in[3];
  const float* bias_table = (const float*)d_in[4];
  float* out = (float*)d_out;

  _Float16* ws = (_Float16*)d_ws;
  _Float16* pos_f  = ws;                     // 2,097,152
  _Float16* wt_pos = ws + 2097152;           // 2,097,152
  _Float16* x_f    = ws + 4194304;           // 4,194,304
  _Float16* wt_tok = ws + 8388608;           // 3,145,728
  _Float16* KG     = ws + 11534336;          // 4,194,304
  _Float16* KGP    = ws + 15728640;          // 2,097,152
  _Float16* VG     = ws + 17825792;          // 4,194,304
  _Float16* QRt    = ws + 22020096;          // 4,194,304
  _Float16* QRp    = ws + 26214400;          // 2,097,152
  // total 28,311,552 halfs = 56.6 MB

  const float QSCALE = 0.08838834764831845f * LOG2E;  // 1/sqrt(2*64) * log2e

  prep_kernel<<<7424, 256, 0, stream>>>(x, pos_embed, W_pos_kq, W_tok_kqv,
                                        x_f, pos_f, wt_pos, wt_tok);
  gemm_all_kernel<<<1024, 256, 0, stream>>>(pos_f, wt_pos, x_f, wt_tok,
                                            KGP, QRp, KG, QRt, VG, QSCALE);
  flash_kernel<<<256, 512, 0, stream>>>(QRt, QRp, KG, KGP, VG, bias_table, out);
}